// Round 1
// 592.633 us; speedup vs baseline: 1.0157x; 1.0157x over previous
//
#include <hip/hip_runtime.h>

// x [4,2048,4096] f32, dna [6] f32, bias [4096] f32, hd [4096,4096] i32,
// out [4,2048,4096] f32. Internally W and X are cast to bf16 for the MFMA GEMM.
#define M_DIM 4096
#define K_DIM 4096
#define NR_DIM 8192
#define TOTAL_ELEMS (M_DIM * K_DIM)

typedef unsigned short u16;
typedef unsigned int u32;
typedef __bf16 bf16x8 __attribute__((ext_vector_type(8)));
typedef float f32x4 __attribute__((ext_vector_type(4)));
typedef u16 u16x8 __attribute__((ext_vector_type(8)));

__device__ __forceinline__ u16 f2b(float f) {
    u32 v;
    __builtin_memcpy(&v, &f, sizeof(v));
    v += 0x7FFFu + ((v >> 16) & 1u);  // round-to-nearest-even
    return (u16)(v >> 16);
}

// Inline |sin|,|cos| via Cody-Waite + minimax polys. Signs are irrelevant
// downstream (fabs), so quadrant handling is a parity swap only.
__device__ __forceinline__ void abs_sincos(float ang, float* s, float* c) {
    float q = rintf(ang * 0.636619772f);
    float r1 = fmaf(q, -1.57079637e+00f, ang);
    float r = fmaf(q, 4.37113883e-08f, r1);
    float r2 = r * r;
    float ts = fmaf(r2, -1.9840874e-04f, 8.3333310e-03f);
    ts = fmaf(r2, ts, -1.6666667e-01f);
    float sp = fmaf(r * r2, ts, r);
    float tc = fmaf(r2, -1.3888378e-03f, 4.1666638e-02f);
    tc = fmaf(r2, tc, -5.0e-01f);
    float cp = fmaf(r2, tc, 1.0f);
    bool sw = (((int)q) & 1) != 0;
    *s = sw ? cp : sp;
    *c = sw ? sp : cp;
}

// FAST path, valid when a==b==1, n1==n2==n3==0.5 (the actual dna):
// r = 1 / (sqrt|cos| + sqrt|sin|)^2. base in [1, 1.68] — no singularity.
__device__ __forceinline__ float compute_r_fast(int d, float c_ang) {
    float s, c;
    abs_sincos((float)d * c_ang, &s, &c);
    float base = __builtin_amdgcn_sqrtf(fabsf(c)) + __builtin_amdgcn_sqrtf(fabsf(s));
    return __builtin_amdgcn_rcpf(base * base);
}

// GENERIC path for arbitrary dna (powf etc.) — wave-uniform-selected, cold.
__device__ __noinline__ float compute_r_gen(int d, float c_ang, float inv_a,
                                            float inv_b, float n2, float n3, float e) {
    float s, c;
    abs_sincos((float)d * c_ang, &s, &c);
    float ca = fabsf(c) * fabsf(inv_a);
    float sb = fabsf(s) * fabsf(inv_b);
    float t1 = (n2 == 0.5f) ? sqrtf(ca) : ((n2 == 1.0f) ? ca : powf(ca, n2));
    float t2 = (n3 == 0.5f) ? sqrtf(sb) : ((n3 == 1.0f) ? sb : powf(sb, n3));
    float base = t1 + t2;
    if (e == -2.0f) { float ib = __builtin_amdgcn_rcpf(base); return ib * ib; }
    if (e == -1.0f) return __builtin_amdgcn_rcpf(base);
    return powf(base, e);
}

__device__ __forceinline__ bool dna_is_fast(const float* p) {
    return (p[1] == 1.0f) & (p[2] == 1.0f) & (p[3] == 0.5f) &
           (p[4] == 0.5f) & (p[5] == 0.5f);
}

// Kernel 1: sum / sum-of-squares of r (hd is a bijection onto [0,2^24)).
__global__ void __launch_bounds__(256) reduce_kernel(const float* __restrict__ dna,
                                                     double* __restrict__ sums) {
    float p[6];
#pragma unroll
    for (int i = 0; i < 6; i++) p[i] = dna[i];
    float c_ang = (float)((double)p[0] * 6.283185307179586 / 67108864.0);

    double s = 0.0, s2 = 0.0;
    int idx = blockIdx.x * blockDim.x + threadIdx.x;
    int stride = gridDim.x * blockDim.x;
    if (dna_is_fast(p)) {
        for (int d = idx; d < TOTAL_ELEMS; d += stride) {
            float r = compute_r_fast(d, c_ang);
            s += (double)r;
            s2 += (double)r * (double)r;
        }
    } else {
        float inv_a = 1.0f / p[1], inv_b = 1.0f / p[2], e = -1.0f / p[3];
        for (int d = idx; d < TOTAL_ELEMS; d += stride) {
            float r = compute_r_gen(d, c_ang, inv_a, inv_b, p[4], p[5], e);
            s += (double)r;
            s2 += (double)r * (double)r;
        }
    }
#pragma unroll
    for (int off = 32; off > 0; off >>= 1) {
        s += __shfl_down(s, off);
        s2 += __shfl_down(s2, off);
    }
    __shared__ double ls[4], ls2[4];
    int lane = threadIdx.x & 63, w = threadIdx.x >> 6;
    if (lane == 0) { ls[w] = s; ls2[w] = s2; }
    __syncthreads();
    if (threadIdx.x == 0) {
        atomicAdd(&sums[0], ls[0] + ls[1] + ls[2] + ls[3]);
        atomicAdd(&sums[1], ls2[0] + ls2[1] + ls2[2] + ls2[3]);
    }
}

// Kernel 2: W[m,k] = (r - mean)/(std_ddof1 + 1e-9) * (1/sqrt(K)), stored bf16.
__global__ void __launch_bounds__(256) build_w_kernel(const int* __restrict__ hd,
                                                      const float* __restrict__ dna,
                                                      const double* __restrict__ sums,
                                                      u16* __restrict__ W) {
    float p[6];
#pragma unroll
    for (int i = 0; i < 6; i++) p[i] = dna[i];
    float c_ang = (float)((double)p[0] * 6.283185307179586 / 67108864.0);

    const double cnt = (double)TOTAL_ELEMS;
    double sum = sums[0], sumsq = sums[1];
    float meanf = (float)(sum / cnt);
    float stdf = (float)sqrt((sumsq - sum * sum / cnt) / (cnt - 1.0));
    float sc = 0.015625f / (stdf + 1e-9f);  // fold 1/sqrt(4096)

    int idx = blockIdx.x * blockDim.x + threadIdx.x;
    int stride = gridDim.x * blockDim.x;
    if (dna_is_fast(p)) {
        for (int i = idx * 4; i < TOTAL_ELEMS; i += stride * 4) {
            int4 d4 = *(const int4*)(hd + i);
            ushort4 o;
            o.x = f2b((compute_r_fast(d4.x, c_ang) - meanf) * sc);
            o.y = f2b((compute_r_fast(d4.y, c_ang) - meanf) * sc);
            o.z = f2b((compute_r_fast(d4.z, c_ang) - meanf) * sc);
            o.w = f2b((compute_r_fast(d4.w, c_ang) - meanf) * sc);
            *(ushort4*)(W + i) = o;
        }
    } else {
        float inv_a = 1.0f / p[1], inv_b = 1.0f / p[2], e = -1.0f / p[3];
        for (int i = idx * 4; i < TOTAL_ELEMS; i += stride * 4) {
            int4 d4 = *(const int4*)(hd + i);
            ushort4 o;
            o.x = f2b((compute_r_gen(d4.x, c_ang, inv_a, inv_b, p[4], p[5], e) - meanf) * sc);
            o.y = f2b((compute_r_gen(d4.y, c_ang, inv_a, inv_b, p[4], p[5], e) - meanf) * sc);
            o.z = f2b((compute_r_gen(d4.z, c_ang, inv_a, inv_b, p[4], p[5], e) - meanf) * sc);
            o.w = f2b((compute_r_gen(d4.w, c_ang, inv_a, inv_b, p[4], p[5], e) - meanf) * sc);
            *(ushort4*)(W + i) = o;
        }
    }
}

// Kernel 3: x f32 -> bf16 (8 elements/thread).
__global__ void __launch_bounds__(256) convert_x_kernel(const float* __restrict__ x,
                                                        u16* __restrict__ xb) {
    int i = (blockIdx.x * blockDim.x + threadIdx.x) * 8;
    const float4* xv = (const float4*)(x + i);
    float4 a = xv[0], b = xv[1];
    u16x8 o;
    o[0] = f2b(a.x); o[1] = f2b(a.y); o[2] = f2b(a.z); o[3] = f2b(a.w);
    o[4] = f2b(b.x); o[5] = f2b(b.y); o[6] = f2b(b.z); o[7] = f2b(b.w);
    *(u16x8*)(xb + i) = o;
}

// ---------------- GEMM: C[NR,M] = X[NR,K] * W[M,K]^T -----------------------
// NEW this round: 256x256 tile, BK=64, 8 waves, 8-phase counted-vmcnt schedule
// (T3+T4) + setprio (T5) + XOR swizzle (T2) + XCD block swizzle (T1).
//
// LDS = 8 slots x 16 KB: {A,B} x {k-half ks=0,1} x {dbuf}. One slot = 256 rows
// x 32 bf16 (row pitch 64 B). Swizzle: stored octet = logical ^ ((row>>1)&3),
// applied on the pre-swizzled GLOBAL source and on the ds_read address
// (global_load_lds dest stays linear).
//
// Schedule invariants (proofs in session journal):
//  * Per K-tile t (buf=t&1), 4 phases: P1={Chalf0,ks0}, P2={Chalf1,ks0},
//    P3={Chalf0,ks1}, P4={Chalf1,ks1}. Stages: P1->(t+1).Abeta, P2->(t+1).Bbeta,
//    P3->(t+2).Aalpha, P4->(t+2).Balpha.
//  * A slot is re-staged >=1 phase after its last read; every wave executes
//    s_waitcnt lgkmcnt(0) BEFORE the phase-end s_barrier, so all pending
//    ds_reads are serviced before any wave can issue the overwriting DMA.
//  * A slot is consumed 5-6 phases after staging; with 1 stage (2 loads) per
//    phase, s_waitcnt vmcnt(8) at each phase end guarantees it has landed
//    while keeping 4 stages in flight across barriers (never vmcnt(0)).
//  * Tail: stages are CLAMPED (re-stage tile 63, harmless data into dead or
//    already-drained slots) instead of skipped, so vmcnt accounting stays
//    steady-state-exact.
#define BM 256
#define BN 256
#define BK 64

__device__ __forceinline__ void gld_lds16(const u16* g, u16* l) {
    __builtin_amdgcn_global_load_lds(
        (const __attribute__((address_space(1))) void*)g,
        (__attribute__((address_space(3))) void*)l,
        16, 0, 0);
}

#define FENCE asm volatile("" ::: "memory")
#define WAIT_LGKM0 asm volatile("s_waitcnt lgkmcnt(0)" ::: "memory")
#define WAIT_VM8 asm volatile("s_waitcnt vmcnt(8)" ::: "memory")

#define LOAD_AF(h, bufv, ks)                                                  \
    _Pragma("unroll") for (int m = 0; m < 4; ++m) {                           \
        int row = wr * 128 + ((h) * 4 + m) * 16 + lrow;                       \
        af[m] = *(const bf16x8*)(&sA[bufv][ks][row * 32 + oA]);               \
    }

#define LOAD_BF(bufv, ks)                                                     \
    _Pragma("unroll") for (int n = 0; n < 4; ++n) {                           \
        int row = wc * 64 + n * 16 + lrow;                                    \
        bfr[n] = *(const bf16x8*)(&sB[bufv][ks][row * 32 + oA]);              \
    }

#define MFMA_HALF(h)                                                          \
    __builtin_amdgcn_s_setprio(1);                                            \
    _Pragma("unroll") for (int m = 0; m < 4; ++m)                             \
        _Pragma("unroll") for (int n = 0; n < 4; ++n)                         \
            acc[(h) * 4 + m][n] = __builtin_amdgcn_mfma_f32_16x16x32_bf16(    \
                af[m], bfr[n], acc[(h) * 4 + m][n], 0, 0, 0);                 \
    __builtin_amdgcn_s_setprio(0)

__global__ void __launch_bounds__(512, 2) gemm_kernel(const u16* __restrict__ A,
                                                      const u16* __restrict__ B,
                                                      const float* __restrict__ bias,
                                                      float* __restrict__ C) {
    __shared__ __align__(16) u16 sA[2][2][BM * 32];  // 64 KB
    __shared__ __align__(16) u16 sB[2][2][BN * 32];  // 64 KB

    const int tid = threadIdx.x;
    const int lane = tid & 63;
    const int wave = tid >> 6;  // 0..7
    const int wr = wave >> 2;   // 0..1 -> 128-row half of C-tile (NR dim)
    const int wc = wave & 3;    // 0..3 -> 64-col quarter of C-tile (M dim)
    const int lrow = lane & 15;
    const int lq = lane >> 4;
    const int oA = ((lq ^ ((lrow >> 1) & 3)) << 3);  // swizzled octet, u16 units

    // XCD-aware bijective swizzle: 512 wg, 8 XCDs, 64 wg per XCD chunk.
    const int flat = blockIdx.y * 16 + blockIdx.x;
    const int swz = (flat & 7) * 64 + (flat >> 3);
    const int bx = swz & 15;   // M tile
    const int by = swz >> 4;   // NR tile
    const int i0 = by * BM;
    const int j0 = bx * BN;

    // Staging: thread writes LDS linearly at 16*tid and 16*(tid+512); the
    // matching slot position is row=(L>>2), stored octet=(L&3); source octet
    // pre-swizzled. olog is identical for both loads (row1=row0+128, 128/2%4==0).
    const int srow0 = tid >> 2;  // 0..127
    const int olog = (tid & 3) ^ ((srow0 >> 1) & 3);
    const int aoff0 = (i0 + srow0) * K_DIM + olog * 8;
    const int aoff1 = aoff0 + 128 * K_DIM;
    const int boff0 = (j0 + srow0) * K_DIM + olog * 8;
    const int boff1 = boff0 + 128 * K_DIM;
    const int lds_l0 = tid * 8;          // u16 units
    const int lds_l1 = (tid + 512) * 8;

    auto stage = [&](const u16* base, int off0, int off1, u16* slot, int kb) {
        gld_lds16(base + off0 + kb, slot + lds_l0);
        gld_lds16(base + off1 + kb, slot + lds_l1);
    };

    const f32x4 vzero = {0.f, 0.f, 0.f, 0.f};
    f32x4 acc[8][4];
#pragma unroll
    for (int a = 0; a < 8; a++)
#pragma unroll
        for (int b = 0; b < 4; b++) acc[a][b] = vzero;

    // Prologue: 6 slot stages (12 loads), then wait for the first 2 slots.
    stage(A, aoff0, aoff1, sA[0][0], 0);    // 0.Aalpha
    stage(B, boff0, boff1, sB[0][0], 0);    // 0.Balpha
    stage(A, aoff0, aoff1, sA[0][1], 32);   // 0.Abeta
    stage(B, boff0, boff1, sB[0][1], 32);   // 0.Bbeta
    stage(A, aoff0, aoff1, sA[1][0], 64);   // 1.Aalpha
    stage(B, boff0, boff1, sB[1][0], 64);   // 1.Balpha
    WAIT_VM8;
    FENCE;
    __builtin_amdgcn_s_barrier();

    for (int kt = 0; kt < K_DIM / BK; ++kt) {
        const int bufv = kt & 1;
        const int kb1 = (kt + 1 < 64 ? kt + 1 : 63) * 64 + 32;  // clamped tail
        const int kb2 = (kt + 2 < 64 ? kt + 2 : 63) * 64;
        bf16x8 af[4], bfr[4];

        // ---- phase 1: ks=0, C-half 0 ----
        LOAD_AF(0, bufv, 0);
        LOAD_BF(bufv, 0);
        stage(A, aoff0, aoff1, sA[bufv ^ 1][1], kb1);
        FENCE;
        __builtin_amdgcn_s_barrier();
        MFMA_HALF(0);
        WAIT_LGKM0;
        WAIT_VM8;
        FENCE;
        __builtin_amdgcn_s_barrier();

        // ---- phase 2: ks=0, C-half 1 (reuses bfr) ----
        LOAD_AF(1, bufv, 0);
        stage(B, boff0, boff1, sB[bufv ^ 1][1], kb1);
        FENCE;
        __builtin_amdgcn_s_barrier();
        MFMA_HALF(1);
        WAIT_LGKM0;
        WAIT_VM8;
        FENCE;
        __builtin_amdgcn_s_barrier();

        // ---- phase 3: ks=1, C-half 0 ----
        LOAD_AF(0, bufv, 1);
        LOAD_BF(bufv, 1);
        stage(A, aoff0, aoff1, sA[bufv][0], kb2);
        FENCE;
        __builtin_amdgcn_s_barrier();
        MFMA_HALF(0);
        WAIT_LGKM0;
        WAIT_VM8;
        FENCE;
        __builtin_amdgcn_s_barrier();

        // ---- phase 4: ks=1, C-half 1 ----
        LOAD_AF(1, bufv, 1);
        stage(B, boff0, boff1, sB[bufv][0], kb2);
        FENCE;
        __builtin_amdgcn_s_barrier();
        MFMA_HALF(1);
        WAIT_LGKM0;
        WAIT_VM8;
        FENCE;
        __builtin_amdgcn_s_barrier();
    }

    // Epilogue: same fragment->C mapping as the harness-verified 128^2 kernel.
#pragma unroll
    for (int ni = 0; ni < 4; ++ni) {
        long j = j0 + wc * 64 + ni * 16 + lrow;
        float bv = bias[j];
#pragma unroll
        for (int mi = 0; mi < 8; ++mi) {
            long ib = i0 + wr * 128 + mi * 16 + lq * 4;
#pragma unroll
            for (int r = 0; r < 4; ++r) {
                C[(ib + r) * M_DIM + j] = acc[mi][ni][r] + bv;
            }
        }
    }
}

extern "C" void kernel_launch(void* const* d_in, const int* in_sizes, int n_in,
                              void* d_out, int out_size, void* d_ws, size_t ws_size,
                              hipStream_t stream) {
    const float* x = (const float*)d_in[0];
    const float* dna = (const float*)d_in[1];
    const float* bias = (const float*)d_in[2];
    const int* hd = (const int*)d_in[3];
    float* out = (float*)d_out;

    double* sums = (double*)d_ws;                                   // 16 B
    u16* W = (u16*)((char*)d_ws + 256);                             // 32 MB bf16
    u16* Xb = (u16*)((char*)d_ws + 256 + (size_t)TOTAL_ELEMS * 2);  // 64 MB bf16

    hipMemsetAsync(d_ws, 0, 256, stream);
    reduce_kernel<<<dim3(1024), dim3(256), 0, stream>>>(dna, sums);
    build_w_kernel<<<dim3(2048), dim3(256), 0, stream>>>(hd, dna, sums, W);
    convert_x_kernel<<<dim3((NR_DIM * K_DIM) / (256 * 8)), dim3(256), 0, stream>>>(x, Xb);
    gemm_kernel<<<dim3(M_DIM / BN, NR_DIM / BM), dim3(512), 0, stream>>>(Xb, W, bias, out);
}